// Round 12
// baseline (179.061 us; speedup 1.0000x reference)
//
#include <hip/hip_runtime.h>
#include <math.h>

#define N_NODES 100000
#define D_INPUT 128
#define FDIM 128
#define A_HEADS 8
#define B_SEGS 512
#define D_OUTPUT 64
#define H_DIM 2304

typedef __attribute__((ext_vector_type(8))) __bf16 bf16x8;
typedef __attribute__((ext_vector_type(4))) float f32x4;

static __device__ inline unsigned short f2bfu(float f) {
    unsigned u = __builtin_bit_cast(unsigned, f);
    u += 0x7fffu + ((u >> 16) & 1u);
    return (unsigned short)(u >> 16);
}
static __device__ inline unsigned packbf(float a, float b) {
    return (unsigned)f2bfu(a) | ((unsigned)f2bfu(b) << 16);
}
static __device__ inline float bfl(unsigned u) {
    unsigned x = u << 16; return __builtin_bit_cast(float, x);
}
static __device__ inline float bfh(unsigned u) {
    unsigned x = u & 0xffff0000u; return __builtin_bit_cast(float, x);
}
static __device__ inline bf16x8 pack8(float4 a, float4 b) {
    union { unsigned u[4]; bf16x8 v; } r;
    r.u[0] = packbf(a.x, a.y); r.u[1] = packbf(a.z, a.w);
    r.u[2] = packbf(b.x, b.y); r.u[3] = packbf(b.z, b.w);
    return r.v;
}

// ---------------- segment boundaries (batch is sorted) ----------------
__global__ void seg_bounds_kernel(const int* __restrict__ batch, int n,
                                  int* __restrict__ seg_start) {
    int b = threadIdx.x;
    if (b > B_SEGS) return;
    int lo = 0, hi = n;
    while (lo < hi) {
        int mid = (lo + hi) >> 1;
        if (batch[mid] < b) lo = mid + 1; else hi = mid;
    }
    seg_start[b] = lo;
}

// ------- one-time weight conversion fp32 -> bf16 (packed u32), global -------
__global__ __launch_bounds__(256) void wconv_kernel(
        const float* __restrict__ W_in, const float* __restrict__ W_a,
        const float* __restrict__ W_out, unsigned* __restrict__ Wb,
        unsigned* __restrict__ Wa, unsigned* __restrict__ Wo,
        unsigned* __restrict__ Wagg) {
    int i = blockIdx.x * 256 + threadIdx.x;
    if (i < 8192) {
        float2 v = *(const float2*)(W_in + (size_t)i * 2);
        Wb[i] = packbf(v.x, v.y);
    } else if (i < 9216) {
        int j = i - 8192;
        if (j < 512) {
            float2 v = *(const float2*)(W_a + (size_t)j * 2);
            Wa[j] = packbf(v.x, v.y);
        } else Wa[j] = 0u;
    } else if (i < 17408) {
        int j = i - 9216;
        int row = j >> 7, cu = j & 127;
        float2 v = *(const float2*)(W_out + (size_t)row * H_DIM + cu * 2);
        Wo[j] = packbf(v.x, v.y);
    } else if (i < 82944) {
        int j = i - 17408;
        int row = j >> 10, cu = j & 1023;
        float2 v = *(const float2*)(W_out + (size_t)row * H_DIM + 256 + cu * 2);
        Wagg[j] = packbf(v.x, v.y);
    }
}

// ---- meganode: 4 blocks per segment (quarter ranges), 256 threads ----
// Weights read as bf16 fragments straight from global (L2-hot, 68KB shared by
// all 2048 blocks). LDS = XP tile + scoref only (19.5KB) -> high co-residency,
// ~3 barriers/block. In-register quarter partial sum/max -> global partials
// (no atomics). launch_bounds(256,2): VGPR cap 128 (cap = 256/min_waves,
// measured R6/R7/R10; floor of 4 would force 64 -> accumulator spill).
__global__ __launch_bounds__(256, 2) void meganode_kernel(
        const float* __restrict__ x, const int* __restrict__ seg_start,
        const float* __restrict__ b_in, const float* __restrict__ b_a,
        const unsigned* __restrict__ Wb, const unsigned* __restrict__ Wa,
        const unsigned* __restrict__ Wo, unsigned short* __restrict__ opart16,
        float* __restrict__ psum, float* __restrict__ pmax) {
    __shared__ __align__(16) unsigned XP[64 * 68];   // xp chunk bf16 (u16 x136)
    __shared__ float scoref[64 * 8];
    unsigned short* XPs = (unsigned short*)XP;

    const int bb = blockIdx.x;            // 0..2047
    const int seg = bb >> 2, q = bb & 3;
    const int s0 = seg_start[seg], s1 = seg_start[seg + 1];
    const int cnt = s1 - s0;
    if (cnt == 0) return;                 // segfinal also early-exits: no reader
    const int qlen = (cnt + 3) >> 2;
    const int hstart = s0 + q * qlen;
    const int hend = min(s1, hstart + qlen);

    const int t = threadIdx.x;
    const int w = t >> 6, l = t & 63, lr = l & 15, lk = l >> 4;
    const int a0 = t >> 6, f2 = t & 63;   // heads a0, a0+4; feats 2f2, 2f2+1

    float binv[8];
#pragma unroll
    for (int nr = 0; nr < 8; ++nr) binv[nr] = b_in[nr * 16 + lr];
    const float ba = b_a[lr & 7];

    const f32x4 z4 = {0.f, 0.f, 0.f, 0.f};
    float sum0 = 0.f, sum1 = 0.f, sum2 = 0.f, sum3 = 0.f;
    float mx0 = -INFINITY, mx1 = -INFINITY, mx2 = -INFINITY, mx3 = -INFINITY;

    for (int c0 = hstart; c0 < hend; c0 += 64) {
        const int rc = min(64, hend - c0);
        const int arowc = min(c0 + w * 16 + lr, hend - 1);

        bf16x8 af[4];
#pragma unroll
        for (int ks = 0; ks < 4; ++ks) {
            const float4* xp4 = (const float4*)(x + (size_t)arowc * 128 + ks * 32 + lk * 8);
            af[ks] = pack8(xp4[0], xp4[1]);
        }
        // xp GEMM (B-frags from global Wb)
        f32x4 acc[8];
#pragma unroll
        for (int nr = 0; nr < 8; ++nr) acc[nr] = z4;
#pragma unroll
        for (int ks = 0; ks < 4; ++ks)
#pragma unroll
            for (int nr = 0; nr < 8; ++nr) {
                bf16x8 bfrag = *(const bf16x8*)&Wb[(nr * 16 + lr) * 64 + ks * 16 + lk * 4];
                acc[nr] = __builtin_amdgcn_mfma_f32_16x16x32_bf16(af[ks], bfrag, acc[nr], 0, 0, 0);
            }
        // bias + XP write (own 16 rows)
#pragma unroll
        for (int nr = 0; nr < 8; ++nr)
#pragma unroll
            for (int r = 0; r < 4; ++r) {
                int row = w * 16 + lk * 4 + r;
                XPs[row * 136 + nr * 16 + lr] = f2bfu(((const float*)&acc[nr])[r] + binv[nr]);
            }
        // own XP rows back as A-frags (same-wave write/read)
        bf16x8 xf[4];
#pragma unroll
        for (int ks = 0; ks < 4; ++ks)
            xf[ks] = *(const bf16x8*)&XPs[(w * 16 + lr) * 136 + ks * 32 + lk * 8];
        // score MFMA (B from global Wa)
        f32x4 sacc = z4;
#pragma unroll
        for (int ks = 0; ks < 4; ++ks) {
            bf16x8 bfrag = *(const bf16x8*)&Wa[lr * 64 + ks * 16 + lk * 4];
            sacc = __builtin_amdgcn_mfma_f32_16x16x32_bf16(xf[ks], bfrag, sacc, 0, 0, 0);
        }
        if (lr < A_HEADS) {
#pragma unroll
            for (int r = 0; r < 4; ++r) {
                int row = w * 16 + lk * 4 + r;
                scoref[row * 8 + lr] = __expf(-fabsf(((const float*)&sacc)[r] + ba));
            }
        }
        // out_part GEMM K=256 (B-frags from global Wo)
        f32x4 aco[4];
#pragma unroll
        for (int nr = 0; nr < 4; ++nr) aco[nr] = z4;
#pragma unroll
        for (int ks = 0; ks < 4; ++ks)
#pragma unroll
            for (int nr = 0; nr < 4; ++nr) {
                bf16x8 b0 = *(const bf16x8*)&Wo[(nr * 16 + lr) * 128 + ks * 16 + lk * 4];
                aco[nr] = __builtin_amdgcn_mfma_f32_16x16x32_bf16(af[ks], b0, aco[nr], 0, 0, 0);
                bf16x8 b1 = *(const bf16x8*)&Wo[(nr * 16 + lr) * 128 + 64 + ks * 16 + lk * 4];
                aco[nr] = __builtin_amdgcn_mfma_f32_16x16x32_bf16(xf[ks], b1, aco[nr], 0, 0, 0);
            }
#pragma unroll
        for (int nr = 0; nr < 4; ++nr)
#pragma unroll
            for (int r = 0; r < 4; ++r) {
                int n = c0 + w * 16 + lk * 4 + r;
                if (n < hend)
                    opart16[(size_t)n * 64 + nr * 16 + lr] = f2bfu(((const float*)&aco[nr])[r]);
            }
        __syncthreads();   // XP + scoref visible to all waves

        // register agg: thread = (heads a0,a0+4; feat pair 2*f2,2*f2+1)
        for (int i = 0; i < rc; ++i) {
            unsigned u = XP[i * 68 + f2];
            float xa = bfl(u), xb = bfh(u);
            float sa = scoref[i * 8 + a0];
            float sb = scoref[i * 8 + a0 + 4];
            float e0 = sa * xa, e1 = sa * xb, e2 = sb * xa, e3 = sb * xb;
            sum0 += e0; sum1 += e1; sum2 += e2; sum3 += e3;
            mx0 = fmaxf(mx0, e0); mx1 = fmaxf(mx1, e1);
            mx2 = fmaxf(mx2, e2); mx3 = fmaxf(mx3, e3);
        }
        __syncthreads();   // before next chunk overwrites XP/scoref
    }

    // partial write (plain coalesced float2; empty quarters write 0/-inf)
    float* ps = psum + (size_t)bb * 1024;
    float* pm = pmax + (size_t)bb * 1024;
    *(float2*)&ps[a0 * 128 + 2 * f2]       = make_float2(sum0, sum1);
    *(float2*)&ps[(a0 + 4) * 128 + 2 * f2] = make_float2(sum2, sum3);
    *(float2*)&pm[a0 * 128 + 2 * f2]       = make_float2(mx0, mx1);
    *(float2*)&pm[(a0 + 4) * 128 + 2 * f2] = make_float2(mx2, mx3);
}

// ---- segfinal: combine 4 partials, mean/max, Wagg projection, emit out ----
__global__ __launch_bounds__(256) void segfinal_kernel(
        const float* __restrict__ psum, const float* __restrict__ pmax,
        const int* __restrict__ seg_start, const unsigned* __restrict__ Wagg,
        const float* __restrict__ b_out, const unsigned* __restrict__ out_part_u32,
        float* __restrict__ out) {
    __shared__ float agg[2048];
    __shared__ float projL[64];
    const int b = blockIdx.x, t = threadIdx.x;
    const int s0 = seg_start[b], s1 = seg_start[b + 1];
    const int cnt = s1 - s0;
    if (cnt == 0) return;
    const float inv = 1.f / (float)cnt;
    const size_t pb = (size_t)(4 * b) * 1024;
#pragma unroll
    for (int i = 0; i < 4; ++i) {
        int idx = i * 256 + t;
        float s = psum[pb + idx] + psum[pb + 1024 + idx]
                + psum[pb + 2048 + idx] + psum[pb + 3072 + idx];
        float m = fmaxf(fmaxf(pmax[pb + idx], pmax[pb + 1024 + idx]),
                        fmaxf(pmax[pb + 2048 + idx], pmax[pb + 3072 + idx]));
        int a = idx >> 7, f = idx & 127;
        agg[a * 256 + f] = s * inv;
        agg[a * 256 + 128 + f] = m;
    }
    __syncthreads();
    // projection via bf16 Wagg: wave -> 16 outputs
    const int wave = t >> 6, lane = t & 63;
#pragma unroll
    for (int i = 0; i < 16; ++i) {
        int o = wave * 16 + i;
        const unsigned* wrow = Wagg + (size_t)o * 1024;
        float partial = 0.f;
#pragma unroll
        for (int c = 0; c < 4; ++c) {
            int j4 = c * 256 + lane * 4;
            uint4 wv = *(const uint4*)&wrow[j4];
            const float* av = &agg[2 * j4];
            partial = fmaf(bfl(wv.x), av[0], partial);
            partial = fmaf(bfh(wv.x), av[1], partial);
            partial = fmaf(bfl(wv.y), av[2], partial);
            partial = fmaf(bfh(wv.y), av[3], partial);
            partial = fmaf(bfl(wv.z), av[4], partial);
            partial = fmaf(bfh(wv.z), av[5], partial);
            partial = fmaf(bfl(wv.w), av[6], partial);
            partial = fmaf(bfh(wv.w), av[7], partial);
        }
#pragma unroll
        for (int m = 1; m < 64; m <<= 1) partial += __shfl_xor(partial, m);
        if (lane == 0) projL[o] = partial + b_out[o];
    }
    __syncthreads();
    // stream: out = relu(out_part + projL) for this segment's rows
    const int rr = t >> 3, cg = t & 7;
    float p[8];
#pragma unroll
    for (int j = 0; j < 8; ++j) p[j] = projL[cg * 8 + j];
    for (int row = s0 + rr; row < s1; row += 32) {
        uint4 v = *(const uint4*)&out_part_u32[(size_t)row * 32 + cg * 4];
        float4 o0, o1;
        o0.x = fmaxf(bfl(v.x) + p[0], 0.f);
        o0.y = fmaxf(bfh(v.x) + p[1], 0.f);
        o0.z = fmaxf(bfl(v.y) + p[2], 0.f);
        o0.w = fmaxf(bfh(v.y) + p[3], 0.f);
        o1.x = fmaxf(bfl(v.z) + p[4], 0.f);
        o1.y = fmaxf(bfh(v.z) + p[5], 0.f);
        o1.z = fmaxf(bfl(v.w) + p[6], 0.f);
        o1.w = fmaxf(bfh(v.w) + p[7], 0.f);
        *(float4*)&out[(size_t)row * 64 + cg * 8] = o0;
        *(float4*)&out[(size_t)row * 64 + cg * 8 + 4] = o1;
    }
}

extern "C" void kernel_launch(void* const* d_in, const int* in_sizes, int n_in,
                              void* d_out, int out_size, void* d_ws, size_t ws_size,
                              hipStream_t stream) {
    const float* x     = (const float*)d_in[0];
    const int*   batch = (const int*)d_in[1];
    const float* W_in  = (const float*)d_in[3];
    const float* b_in  = (const float*)d_in[4];
    const float* W_a   = (const float*)d_in[5];
    const float* b_a   = (const float*)d_in[6];
    const float* W_out = (const float*)d_in[7];
    const float* b_out = (const float*)d_in[8];
    float* out = (float*)d_out;

    int* seg_start  = (int*)d_ws;                            // 520 ints
    unsigned* Wb    = (unsigned*)(seg_start + 520);          // 8192
    unsigned* Wa    = Wb + 8192;                             // 1024
    unsigned* Wo    = Wa + 1024;                             // 8192
    unsigned* Wagg  = Wo + 8192;                             // 65536
    float* psum     = (float*)(Wagg + 65536);                // 2048*1024
    float* pmax     = psum + 2048 * 1024;                    // 2048*1024
    unsigned* out_part_u32 = (unsigned*)(pmax + 2048 * 1024);// N*32 u32
    unsigned short* opart16 = (unsigned short*)out_part_u32;

    seg_bounds_kernel<<<1, 1024, 0, stream>>>(batch, N_NODES, seg_start);
    wconv_kernel<<<324, 256, 0, stream>>>(W_in, W_a, W_out, Wb, Wa, Wo, Wagg);
    meganode_kernel<<<4 * B_SEGS, 256, 0, stream>>>(
        x, seg_start, b_in, b_a, Wb, Wa, Wo, opart16, psum, pmax);
    segfinal_kernel<<<B_SEGS, 256, 0, stream>>>(
        psum, pmax, seg_start, Wagg, b_out, out_part_u32, out);
}

// Round 13
// 77.297 us; speedup vs baseline: 2.3165x; 2.3165x over previous
//
#include <hip/hip_runtime.h>
#include <math.h>

#define N_NODES 100000
#define D_INPUT 128
#define FDIM 128
#define A_HEADS 8
#define B_SEGS 512
#define D_OUTPUT 64
#define H_DIM 2304

typedef __attribute__((ext_vector_type(8))) __bf16 bf16x8;
typedef __attribute__((ext_vector_type(4))) float f32x4;

static __device__ inline unsigned short f2bfu(float f) {
    unsigned u = __builtin_bit_cast(unsigned, f);
    u += 0x7fffu + ((u >> 16) & 1u);
    return (unsigned short)(u >> 16);
}
static __device__ inline unsigned packbf(float a, float b) {
    return (unsigned)f2bfu(a) | ((unsigned)f2bfu(b) << 16);
}
static __device__ inline float bfl(unsigned u) {
    unsigned x = u << 16; return __builtin_bit_cast(float, x);
}
static __device__ inline float bfh(unsigned u) {
    unsigned x = u & 0xffff0000u; return __builtin_bit_cast(float, x);
}
static __device__ inline bf16x8 pack8(float4 a, float4 b) {
    union { unsigned u[4]; bf16x8 v; } r;
    r.u[0] = packbf(a.x, a.y); r.u[1] = packbf(a.z, a.w);
    r.u[2] = packbf(b.x, b.y); r.u[3] = packbf(b.z, b.w);
    return r.v;
}

// ---------------- segment boundaries (batch is sorted) ----------------
__global__ void seg_bounds_kernel(const int* __restrict__ batch, int n,
                                  int* __restrict__ seg_start) {
    int b = threadIdx.x;
    if (b > B_SEGS) return;
    int lo = 0, hi = n;
    while (lo < hi) {
        int mid = (lo + hi) >> 1;
        if (batch[mid] < b) lo = mid + 1; else hi = mid;
    }
    seg_start[b] = lo;
}

// ------- one-time weight conversion fp32 -> bf16 (packed u32), global -------
__global__ __launch_bounds__(256) void wconv_kernel(
        const float* __restrict__ W_in, const float* __restrict__ W_a,
        const float* __restrict__ W_out, unsigned* __restrict__ Wb,
        unsigned* __restrict__ Wa, unsigned* __restrict__ Wo,
        unsigned* __restrict__ Wagg) {
    int i = blockIdx.x * 256 + threadIdx.x;
    if (i < 8192) {
        float2 v = *(const float2*)(W_in + (size_t)i * 2);
        Wb[i] = packbf(v.x, v.y);
    } else if (i < 9216) {
        int j = i - 8192;
        if (j < 512) {
            float2 v = *(const float2*)(W_a + (size_t)j * 2);
            Wa[j] = packbf(v.x, v.y);
        } else Wa[j] = 0u;
    } else if (i < 17408) {
        int j = i - 9216;
        int row = j >> 7, cu = j & 127;
        float2 v = *(const float2*)(W_out + (size_t)row * H_DIM + cu * 2);
        Wo[j] = packbf(v.x, v.y);
    } else if (i < 82944) {
        int j = i - 17408;
        int row = j >> 10, cu = j & 1023;
        float2 v = *(const float2*)(W_out + (size_t)row * H_DIM + 256 + cu * 2);
        Wagg[j] = packbf(v.x, v.y);
    }
}

// ---- segment-major mega: one block per segment, 1024 threads (16 waves) ----
// R11 per-thread body (proven 88 VGPR, no spill), R5 padded LDS strides (no
// swizzle), preconverted bf16 weights, fused tail. 16 waves/CU co-resident
// by construction; 256-row chunks -> nearly all segments need ONE chunk.
// launch_bounds(1024) alone: hard VGPR cap 128 (16-wave block must fit CU).
__global__ __launch_bounds__(1024) void mega_kernel(
        const float* __restrict__ x, const int* __restrict__ seg_start,
        const float* __restrict__ b_in, const float* __restrict__ b_a,
        const float* __restrict__ b_out, const unsigned* __restrict__ Wb,
        const unsigned* __restrict__ Wa, const unsigned* __restrict__ Wo,
        const unsigned* __restrict__ Wagg, unsigned* __restrict__ out_part_u32,
        float* __restrict__ out) {
    __shared__ __align__(16) unsigned WbL[128 * 68];   // W_in bf16
    __shared__ __align__(16) unsigned WaL[16 * 68];    // W_a bf16 (8..15 zero)
    __shared__ __align__(16) unsigned WoL[64 * 132];   // W_out[:, :256] bf16
    __shared__ __align__(16) unsigned XP[256 * 68];    // xp chunk bf16 / agg f32
    __shared__ float scoref[256 * 8];                  // scores / merge buffer
    __shared__ float projL[64];
    unsigned short* XPs = (unsigned short*)XP;
    float* XPf = (float*)XP;
    unsigned short* opart16 = (unsigned short*)out_part_u32;

    const int b = blockIdx.x;
    const int s0 = seg_start[b], s1 = seg_start[b + 1];
    const int cnt = s1 - s0;
    if (cnt == 0) return;
    const int t = threadIdx.x;

    // ---- stage weights: pure uint4 copies from pre-converted bf16 global ----
    {
        const uint4* srcb = (const uint4*)Wb;      // 2048 uint4, 16 per row
#pragma unroll
        for (int i = 0; i < 2; ++i) {
            int idx = i * 1024 + t;
            int row = idx >> 4, c4 = idx & 15;
            *(uint4*)&WbL[row * 68 + c4 * 4] = srcb[idx];
        }
        const uint4* srco = (const uint4*)Wo;      // 2048 uint4, 32 per row
#pragma unroll
        for (int i = 0; i < 2; ++i) {
            int idx = i * 1024 + t;
            int row = idx >> 5, c4 = idx & 31;
            *(uint4*)&WoL[row * 132 + c4 * 4] = srco[idx];
        }
        if (t < 256) {                             // Wa: 256 uint4, 16 per row
            const uint4* sa = (const uint4*)Wa;
            int row = t >> 4, c4 = t & 15;
            *(uint4*)&WaL[row * 68 + c4 * 4] = sa[t];
        }
    }
    __syncthreads();

    const int w = t >> 6, l = t & 63, lr = l & 15, lk = l >> 4;
    // agg ownership: slot in [0,512): head a0, feat-pair f2; group g = row parity
    const int slot = t & 511, a0 = slot >> 6, f2 = slot & 63, g = t >> 9;

    float binv[8];
#pragma unroll
    for (int nr = 0; nr < 8; ++nr) binv[nr] = b_in[nr * 16 + lr];
    const float ba = b_a[lr & 7];

    const f32x4 z4 = {0.f, 0.f, 0.f, 0.f};
    float sum0 = 0.f, sum1 = 0.f, mx0 = -INFINITY, mx1 = -INFINITY;

    for (int c0 = s0; c0 < s1; c0 += 256) {
        const int rc = min(256, s1 - c0);
        const int arowc = min(c0 + w * 16 + lr, s1 - 1);

        bf16x8 af[4];
#pragma unroll
        for (int ks = 0; ks < 4; ++ks) {
            const float4* xp4 = (const float4*)(x + (size_t)arowc * 128 + ks * 32 + lk * 8);
            af[ks] = pack8(xp4[0], xp4[1]);
        }

        // xp GEMM in two nr-halves (acc[4] caps register pressure; proven)
#pragma unroll
        for (int nh = 0; nh < 2; ++nh) {
            f32x4 acc[4];
#pragma unroll
            for (int nr = 0; nr < 4; ++nr) acc[nr] = z4;
#pragma unroll
            for (int ks = 0; ks < 4; ++ks)
#pragma unroll
                for (int nr = 0; nr < 4; ++nr) {
                    bf16x8 bfrag = *(const bf16x8*)&WbL[((nh * 4 + nr) * 16 + lr) * 68 + ks * 16 + lk * 4];
                    acc[nr] = __builtin_amdgcn_mfma_f32_16x16x32_bf16(af[ks], bfrag, acc[nr], 0, 0, 0);
                }
#pragma unroll
            for (int nr = 0; nr < 4; ++nr)
#pragma unroll
                for (int r = 0; r < 4; ++r) {
                    int row = w * 16 + lk * 4 + r;
                    XPs[row * 136 + (nh * 4 + nr) * 16 + lr] =
                        f2bfu(((const float*)&acc[nr])[r] + binv[nh * 4 + nr]);
                }
        }
        // own XP rows back as A-frags (same-wave write/read)
        bf16x8 xf[4];
#pragma unroll
        for (int ks = 0; ks < 4; ++ks)
            xf[ks] = *(const bf16x8*)&XPs[(w * 16 + lr) * 136 + ks * 32 + lk * 8];
        // score MFMA
        f32x4 sacc = z4;
#pragma unroll
        for (int ks = 0; ks < 4; ++ks) {
            bf16x8 bfrag = *(const bf16x8*)&WaL[lr * 68 + ks * 16 + lk * 4];
            sacc = __builtin_amdgcn_mfma_f32_16x16x32_bf16(xf[ks], bfrag, sacc, 0, 0, 0);
        }
        if (lr < A_HEADS) {
#pragma unroll
            for (int r = 0; r < 4; ++r) {
                int row = w * 16 + lk * 4 + r;
                scoref[row * 8 + lr] = __expf(-fabsf(((const float*)&sacc)[r] + ba));
            }
        }
        // out_part GEMM K=256 (B-frags from LDS WoL)
        f32x4 aco[4];
#pragma unroll
        for (int nr = 0; nr < 4; ++nr) aco[nr] = z4;
#pragma unroll
        for (int ks = 0; ks < 4; ++ks)
#pragma unroll
            for (int nr = 0; nr < 4; ++nr) {
                bf16x8 b0 = *(const bf16x8*)&WoL[(nr * 16 + lr) * 132 + ks * 16 + lk * 4];
                aco[nr] = __builtin_amdgcn_mfma_f32_16x16x32_bf16(af[ks], b0, aco[nr], 0, 0, 0);
                bf16x8 b1 = *(const bf16x8*)&WoL[(nr * 16 + lr) * 132 + 64 + ks * 16 + lk * 4];
                aco[nr] = __builtin_amdgcn_mfma_f32_16x16x32_bf16(xf[ks], b1, aco[nr], 0, 0, 0);
            }
#pragma unroll
        for (int nr = 0; nr < 4; ++nr)
#pragma unroll
            for (int r = 0; r < 4; ++r) {
                int n = c0 + w * 16 + lk * 4 + r;
                if (n < s1)
                    opart16[(size_t)n * 64 + nr * 16 + lr] = f2bfu(((const float*)&aco[nr])[r]);
            }
        __syncthreads();   // XP + scoref visible to all waves

        // register agg: slot=(a0, f2), group g takes rows i ≡ g (mod 2)
        for (int i = g; i < rc; i += 2) {
            unsigned u = XP[i * 68 + f2];
            float sa = scoref[i * 8 + a0];
            float e0 = sa * bfl(u), e1 = sa * bfh(u);
            sum0 += e0; sum1 += e1;
            mx0 = fmaxf(mx0, e0); mx1 = fmaxf(mx1, e1);
        }
        __syncthreads();   // before next chunk overwrites XP/scoref
    }

    // ---- merge g=1 partials into g=0 via scoref buffer (512 slots x 4) ----
    if (g == 1) {
        float4 v = make_float4(sum0, sum1, mx0, mx1);
        *(float4*)&scoref[slot * 4] = v;
    }
    __syncthreads();
    if (g == 0) {
        float4 v = *(const float4*)&scoref[slot * 4];
        sum0 += v.x; sum1 += v.y;
        mx0 = fmaxf(mx0, v.z); mx1 = fmaxf(mx1, v.w);
        const float inv = 1.f / (float)cnt;
        XPf[a0 * 256 + 2 * f2]           = sum0 * inv;
        XPf[a0 * 256 + 2 * f2 + 1]       = sum1 * inv;
        XPf[a0 * 256 + 128 + 2 * f2]     = mx0;
        XPf[a0 * 256 + 128 + 2 * f2 + 1] = mx1;
    }
    __syncthreads();

    // ---- projection via bf16 Wagg (global, L2-hot): wave w -> 4 outputs ----
#pragma unroll
    for (int i = 0; i < 4; ++i) {
        int o = w * 4 + i;
        const unsigned* wrow = Wagg + (size_t)o * 1024;
        float partial = 0.f;
#pragma unroll
        for (int c = 0; c < 4; ++c) {
            int j4 = c * 256 + l * 4;
            uint4 wv = *(const uint4*)&wrow[j4];
            const float* av = &XPf[2 * j4];
            partial = fmaf(bfl(wv.x), av[0], partial);
            partial = fmaf(bfh(wv.x), av[1], partial);
            partial = fmaf(bfl(wv.y), av[2], partial);
            partial = fmaf(bfh(wv.y), av[3], partial);
            partial = fmaf(bfl(wv.z), av[4], partial);
            partial = fmaf(bfh(wv.z), av[5], partial);
            partial = fmaf(bfl(wv.w), av[6], partial);
            partial = fmaf(bfh(wv.w), av[7], partial);
        }
#pragma unroll
        for (int m = 1; m < 64; m <<= 1) partial += __shfl_xor(partial, m);
        if (l == 0) projL[o] = partial + b_out[o];
    }
    __syncthreads();

    // ---- final: out = relu(out_part + projL) for own rows ----
    const int rr = t >> 3, cg = t & 7;   // 128 row-slots x 8 col-groups
    float p[8];
#pragma unroll
    for (int j = 0; j < 8; ++j) p[j] = projL[cg * 8 + j];
    for (int row = s0 + rr; row < s1; row += 128) {
        uint4 v = *(const uint4*)&out_part_u32[(size_t)row * 32 + cg * 4];
        float4 o0, o1;
        o0.x = fmaxf(bfl(v.x) + p[0], 0.f);
        o0.y = fmaxf(bfh(v.x) + p[1], 0.f);
        o0.z = fmaxf(bfl(v.y) + p[2], 0.f);
        o0.w = fmaxf(bfh(v.y) + p[3], 0.f);
        o1.x = fmaxf(bfl(v.z) + p[4], 0.f);
        o1.y = fmaxf(bfh(v.z) + p[5], 0.f);
        o1.z = fmaxf(bfl(v.w) + p[6], 0.f);
        o1.w = fmaxf(bfh(v.w) + p[7], 0.f);
        *(float4*)&out[(size_t)row * 64 + cg * 8] = o0;
        *(float4*)&out[(size_t)row * 64 + cg * 8 + 4] = o1;
    }
}

extern "C" void kernel_launch(void* const* d_in, const int* in_sizes, int n_in,
                              void* d_out, int out_size, void* d_ws, size_t ws_size,
                              hipStream_t stream) {
    const float* x     = (const float*)d_in[0];
    const int*   batch = (const int*)d_in[1];
    const float* W_in  = (const float*)d_in[3];
    const float* b_in  = (const float*)d_in[4];
    const float* W_a   = (const float*)d_in[5];
    const float* b_a   = (const float*)d_in[6];
    const float* W_out = (const float*)d_in[7];
    const float* b_out = (const float*)d_in[8];
    float* out = (float*)d_out;

    int* seg_start  = (int*)d_ws;                            // 520 ints
    unsigned* Wb    = (unsigned*)(seg_start + 520);          // 8192
    unsigned* Wa    = Wb + 8192;                             // 1024
    unsigned* Wo    = Wa + 1024;                             // 8192
    unsigned* Wagg  = Wo + 8192;                             // 65536
    unsigned* out_part_u32 = Wagg + 65536;                   // N*32 u32

    seg_bounds_kernel<<<1, 1024, 0, stream>>>(batch, N_NODES, seg_start);
    wconv_kernel<<<324, 256, 0, stream>>>(W_in, W_a, W_out, Wb, Wa, Wo, Wagg);
    mega_kernel<<<B_SEGS, 1024, 0, stream>>>(
        x, seg_start, b_in, b_a, b_out, Wb, Wa, Wo, Wagg, out_part_u32, out);
}

// Round 14
// 76.882 us; speedup vs baseline: 2.3290x; 1.0054x over previous
//
#include <hip/hip_runtime.h>
#include <math.h>

#define N_NODES 100000
#define D_INPUT 128
#define FDIM 128
#define A_HEADS 8
#define B_SEGS 512
#define D_OUTPUT 64
#define H_DIM 2304

typedef __attribute__((ext_vector_type(8))) __bf16 bf16x8;
typedef __attribute__((ext_vector_type(4))) float f32x4;

static __device__ inline unsigned short f2bfu(float f) {
    unsigned u = __builtin_bit_cast(unsigned, f);
    u += 0x7fffu + ((u >> 16) & 1u);
    return (unsigned short)(u >> 16);
}
static __device__ inline unsigned packbf(float a, float b) {
    return (unsigned)f2bfu(a) | ((unsigned)f2bfu(b) << 16);
}
static __device__ inline float bfl(unsigned u) {
    unsigned x = u << 16; return __builtin_bit_cast(float, x);
}
static __device__ inline float bfh(unsigned u) {
    unsigned x = u & 0xffff0000u; return __builtin_bit_cast(float, x);
}
static __device__ inline bf16x8 pack8(float4 a, float4 b) {
    union { unsigned u[4]; bf16x8 v; } r;
    r.u[0] = packbf(a.x, a.y); r.u[1] = packbf(a.z, a.w);
    r.u[2] = packbf(b.x, b.y); r.u[3] = packbf(b.z, b.w);
    return r.v;
}

// ---------------- segment boundaries (batch is sorted) ----------------
__global__ void seg_bounds_kernel(const int* __restrict__ batch, int n,
                                  int* __restrict__ seg_start) {
    int b = threadIdx.x;
    if (b > B_SEGS) return;
    int lo = 0, hi = n;
    while (lo < hi) {
        int mid = (lo + hi) >> 1;
        if (batch[mid] < b) lo = mid + 1; else hi = mid;
    }
    seg_start[b] = lo;
}

// ------- one-time weight conversion fp32 -> bf16 (packed u32), global -------
__global__ __launch_bounds__(256) void wconv_kernel(
        const float* __restrict__ W_in, const float* __restrict__ W_a,
        const float* __restrict__ W_out, unsigned* __restrict__ Wb,
        unsigned* __restrict__ Wa, unsigned* __restrict__ Wo,
        unsigned* __restrict__ Wagg) {
    int i = blockIdx.x * 256 + threadIdx.x;
    if (i < 8192) {
        float2 v = *(const float2*)(W_in + (size_t)i * 2);
        Wb[i] = packbf(v.x, v.y);
    } else if (i < 9216) {
        int j = i - 8192;
        if (j < 512) {
            float2 v = *(const float2*)(W_a + (size_t)j * 2);
            Wa[j] = packbf(v.x, v.y);
        } else Wa[j] = 0u;
    } else if (i < 17408) {
        int j = i - 9216;
        int row = j >> 7, cu = j & 127;
        float2 v = *(const float2*)(W_out + (size_t)row * H_DIM + cu * 2);
        Wo[j] = packbf(v.x, v.y);
    } else if (i < 82944) {
        int j = i - 17408;
        int row = j >> 10, cu = j & 1023;
        float2 v = *(const float2*)(W_out + (size_t)row * H_DIM + 256 + cu * 2);
        Wagg[j] = packbf(v.x, v.y);
    }
}

// ---- segment-major mega: one block per segment, 1024 threads (16 waves) ----
// R11 per-thread body (proven 88 VGPR, no spill), R5 padded LDS strides (no
// swizzle), preconverted bf16 weights, fused tail. 16 waves/CU co-resident
// by construction; 256-row chunks -> nearly all segments need ONE chunk.
// launch_bounds(1024) alone: hard VGPR cap 128 (16-wave block must fit CU).
__global__ __launch_bounds__(1024) void mega_kernel(
        const float* __restrict__ x, const int* __restrict__ seg_start,
        const float* __restrict__ b_in, const float* __restrict__ b_a,
        const float* __restrict__ b_out, const unsigned* __restrict__ Wb,
        const unsigned* __restrict__ Wa, const unsigned* __restrict__ Wo,
        const unsigned* __restrict__ Wagg, unsigned* __restrict__ out_part_u32,
        float* __restrict__ out) {
    __shared__ __align__(16) unsigned WbL[128 * 68];   // W_in bf16
    __shared__ __align__(16) unsigned WaL[16 * 68];    // W_a bf16 (8..15 zero)
    __shared__ __align__(16) unsigned WoL[64 * 132];   // W_out[:, :256] bf16
    __shared__ __align__(16) unsigned XP[256 * 68];    // xp chunk bf16 / agg f32
    __shared__ float scoref[256 * 8];                  // scores / merge buffer
    __shared__ float projL[64];
    unsigned short* XPs = (unsigned short*)XP;
    float* XPf = (float*)XP;
    unsigned short* opart16 = (unsigned short*)out_part_u32;

    const int b = blockIdx.x;
    const int s0 = seg_start[b], s1 = seg_start[b + 1];
    const int cnt = s1 - s0;
    if (cnt == 0) return;
    const int t = threadIdx.x;

    // ---- stage weights: pure uint4 copies from pre-converted bf16 global ----
    {
        const uint4* srcb = (const uint4*)Wb;      // 2048 uint4, 16 per row
#pragma unroll
        for (int i = 0; i < 2; ++i) {
            int idx = i * 1024 + t;
            int row = idx >> 4, c4 = idx & 15;
            *(uint4*)&WbL[row * 68 + c4 * 4] = srcb[idx];
        }
        const uint4* srco = (const uint4*)Wo;      // 2048 uint4, 32 per row
#pragma unroll
        for (int i = 0; i < 2; ++i) {
            int idx = i * 1024 + t;
            int row = idx >> 5, c4 = idx & 31;
            *(uint4*)&WoL[row * 132 + c4 * 4] = srco[idx];
        }
        if (t < 256) {                             // Wa: 256 uint4, 16 per row
            const uint4* sa = (const uint4*)Wa;
            int row = t >> 4, c4 = t & 15;
            *(uint4*)&WaL[row * 68 + c4 * 4] = sa[t];
        }
    }
    __syncthreads();

    const int w = t >> 6, l = t & 63, lr = l & 15, lk = l >> 4;
    // agg ownership: slot in [0,512): head a0, feat-pair f2; group g = row parity
    const int slot = t & 511, a0 = slot >> 6, f2 = slot & 63, g = t >> 9;

    float binv[8];
#pragma unroll
    for (int nr = 0; nr < 8; ++nr) binv[nr] = b_in[nr * 16 + lr];
    const float ba = b_a[lr & 7];

    const f32x4 z4 = {0.f, 0.f, 0.f, 0.f};
    float sum0 = 0.f, sum1 = 0.f, mx0 = -INFINITY, mx1 = -INFINITY;

    for (int c0 = s0; c0 < s1; c0 += 256) {
        const int rc = min(256, s1 - c0);
        const int arowc = min(c0 + w * 16 + lr, s1 - 1);

        bf16x8 af[4];
#pragma unroll
        for (int ks = 0; ks < 4; ++ks) {
            const float4* xp4 = (const float4*)(x + (size_t)arowc * 128 + ks * 32 + lk * 8);
            af[ks] = pack8(xp4[0], xp4[1]);
        }

        // xp GEMM in two nr-halves (acc[4] caps register pressure; proven)
#pragma unroll
        for (int nh = 0; nh < 2; ++nh) {
            f32x4 acc[4];
#pragma unroll
            for (int nr = 0; nr < 4; ++nr) acc[nr] = z4;
#pragma unroll
            for (int ks = 0; ks < 4; ++ks)
#pragma unroll
                for (int nr = 0; nr < 4; ++nr) {
                    bf16x8 bfrag = *(const bf16x8*)&WbL[((nh * 4 + nr) * 16 + lr) * 68 + ks * 16 + lk * 4];
                    acc[nr] = __builtin_amdgcn_mfma_f32_16x16x32_bf16(af[ks], bfrag, acc[nr], 0, 0, 0);
                }
#pragma unroll
            for (int nr = 0; nr < 4; ++nr)
#pragma unroll
                for (int r = 0; r < 4; ++r) {
                    int row = w * 16 + lk * 4 + r;
                    XPs[row * 136 + (nh * 4 + nr) * 16 + lr] =
                        f2bfu(((const float*)&acc[nr])[r] + binv[nh * 4 + nr]);
                }
        }
        // own XP rows back as A-frags (same-wave write/read)
        bf16x8 xf[4];
#pragma unroll
        for (int ks = 0; ks < 4; ++ks)
            xf[ks] = *(const bf16x8*)&XPs[(w * 16 + lr) * 136 + ks * 32 + lk * 8];
        // score MFMA
        f32x4 sacc = z4;
#pragma unroll
        for (int ks = 0; ks < 4; ++ks) {
            bf16x8 bfrag = *(const bf16x8*)&WaL[lr * 68 + ks * 16 + lk * 4];
            sacc = __builtin_amdgcn_mfma_f32_16x16x32_bf16(xf[ks], bfrag, sacc, 0, 0, 0);
        }
        if (lr < A_HEADS) {
#pragma unroll
            for (int r = 0; r < 4; ++r) {
                int row = w * 16 + lk * 4 + r;
                scoref[row * 8 + lr] = __expf(-fabsf(((const float*)&sacc)[r] + ba));
            }
        }
        // out_part GEMM K=256 (B-frags from LDS WoL)
        f32x4 aco[4];
#pragma unroll
        for (int nr = 0; nr < 4; ++nr) aco[nr] = z4;
#pragma unroll
        for (int ks = 0; ks < 4; ++ks)
#pragma unroll
            for (int nr = 0; nr < 4; ++nr) {
                bf16x8 b0 = *(const bf16x8*)&WoL[(nr * 16 + lr) * 132 + ks * 16 + lk * 4];
                aco[nr] = __builtin_amdgcn_mfma_f32_16x16x32_bf16(af[ks], b0, aco[nr], 0, 0, 0);
                bf16x8 b1 = *(const bf16x8*)&WoL[(nr * 16 + lr) * 132 + 64 + ks * 16 + lk * 4];
                aco[nr] = __builtin_amdgcn_mfma_f32_16x16x32_bf16(xf[ks], b1, aco[nr], 0, 0, 0);
            }
#pragma unroll
        for (int nr = 0; nr < 4; ++nr)
#pragma unroll
            for (int r = 0; r < 4; ++r) {
                int n = c0 + w * 16 + lk * 4 + r;
                if (n < s1)
                    opart16[(size_t)n * 64 + nr * 16 + lr] = f2bfu(((const float*)&aco[nr])[r]);
            }
        __syncthreads();   // XP + scoref visible to all waves

        // register agg: slot=(a0, f2), group g takes rows i ≡ g (mod 2)
        for (int i = g; i < rc; i += 2) {
            unsigned u = XP[i * 68 + f2];
            float sa = scoref[i * 8 + a0];
            float e0 = sa * bfl(u), e1 = sa * bfh(u);
            sum0 += e0; sum1 += e1;
            mx0 = fmaxf(mx0, e0); mx1 = fmaxf(mx1, e1);
        }
        __syncthreads();   // before next chunk overwrites XP/scoref
    }

    // ---- merge g=1 partials into g=0 via scoref buffer (512 slots x 4) ----
    if (g == 1) {
        float4 v = make_float4(sum0, sum1, mx0, mx1);
        *(float4*)&scoref[slot * 4] = v;
    }
    __syncthreads();
    if (g == 0) {
        float4 v = *(const float4*)&scoref[slot * 4];
        sum0 += v.x; sum1 += v.y;
        mx0 = fmaxf(mx0, v.z); mx1 = fmaxf(mx1, v.w);
        const float inv = 1.f / (float)cnt;
        XPf[a0 * 256 + 2 * f2]           = sum0 * inv;
        XPf[a0 * 256 + 2 * f2 + 1]       = sum1 * inv;
        XPf[a0 * 256 + 128 + 2 * f2]     = mx0;
        XPf[a0 * 256 + 128 + 2 * f2 + 1] = mx1;
    }
    __syncthreads();

    // ---- projection via bf16 Wagg (global, L2-hot): wave w -> 4 outputs ----
#pragma unroll
    for (int i = 0; i < 4; ++i) {
        int o = w * 4 + i;
        const unsigned* wrow = Wagg + (size_t)o * 1024;
        float partial = 0.f;
#pragma unroll
        for (int c = 0; c < 4; ++c) {
            int j4 = c * 256 + l * 4;
            uint4 wv = *(const uint4*)&wrow[j4];
            const float* av = &XPf[2 * j4];
            partial = fmaf(bfl(wv.x), av[0], partial);
            partial = fmaf(bfh(wv.x), av[1], partial);
            partial = fmaf(bfl(wv.y), av[2], partial);
            partial = fmaf(bfh(wv.y), av[3], partial);
            partial = fmaf(bfl(wv.z), av[4], partial);
            partial = fmaf(bfh(wv.z), av[5], partial);
            partial = fmaf(bfl(wv.w), av[6], partial);
            partial = fmaf(bfh(wv.w), av[7], partial);
        }
#pragma unroll
        for (int m = 1; m < 64; m <<= 1) partial += __shfl_xor(partial, m);
        if (l == 0) projL[o] = partial + b_out[o];
    }
    __syncthreads();

    // ---- final: out = relu(out_part + projL) for own rows ----
    const int rr = t >> 3, cg = t & 7;   // 128 row-slots x 8 col-groups
    float p[8];
#pragma unroll
    for (int j = 0; j < 8; ++j) p[j] = projL[cg * 8 + j];
    for (int row = s0 + rr; row < s1; row += 128) {
        uint4 v = *(const uint4*)&out_part_u32[(size_t)row * 32 + cg * 4];
        float4 o0, o1;
        o0.x = fmaxf(bfl(v.x) + p[0], 0.f);
        o0.y = fmaxf(bfh(v.x) + p[1], 0.f);
        o0.z = fmaxf(bfl(v.y) + p[2], 0.f);
        o0.w = fmaxf(bfh(v.y) + p[3], 0.f);
        o1.x = fmaxf(bfl(v.z) + p[4], 0.f);
        o1.y = fmaxf(bfh(v.z) + p[5], 0.f);
        o1.z = fmaxf(bfl(v.w) + p[6], 0.f);
        o1.w = fmaxf(bfh(v.w) + p[7], 0.f);
        *(float4*)&out[(size_t)row * 64 + cg * 8] = o0;
        *(float4*)&out[(size_t)row * 64 + cg * 8 + 4] = o1;
    }
}

extern "C" void kernel_launch(void* const* d_in, const int* in_sizes, int n_in,
                              void* d_out, int out_size, void* d_ws, size_t ws_size,
                              hipStream_t stream) {
    const float* x     = (const float*)d_in[0];
    const int*   batch = (const int*)d_in[1];
    const float* W_in  = (const float*)d_in[3];
    const float* b_in  = (const float*)d_in[4];
    const float* W_a   = (const float*)d_in[5];
    const float* b_a   = (const float*)d_in[6];
    const float* W_out = (const float*)d_in[7];
    const float* b_out = (const float*)d_in[8];
    float* out = (float*)d_out;

    int* seg_start  = (int*)d_ws;                            // 520 ints
    unsigned* Wb    = (unsigned*)(seg_start + 520);          // 8192
    unsigned* Wa    = Wb + 8192;                             // 1024
    unsigned* Wo    = Wa + 1024;                             // 8192
    unsigned* Wagg  = Wo + 8192;                             // 65536
    unsigned* out_part_u32 = Wagg + 65536;                   // N*32 u32

    seg_bounds_kernel<<<1, 1024, 0, stream>>>(batch, N_NODES, seg_start);
    wconv_kernel<<<324, 256, 0, stream>>>(W_in, W_a, W_out, Wb, Wa, Wo, Wagg);
    mega_kernel<<<B_SEGS, 1024, 0, stream>>>(
        x, seg_start, b_in, b_a, b_out, Wb, Wa, Wo, Wagg, out_part_u32, out);
}

// Round 15
// 66.891 us; speedup vs baseline: 2.6769x; 1.1494x over previous
//
#include <hip/hip_runtime.h>
#include <math.h>

#define N_NODES 100000
#define D_INPUT 128
#define FDIM 128
#define A_HEADS 8
#define B_SEGS 512
#define D_OUTPUT 64
#define H_DIM 2304

typedef __attribute__((ext_vector_type(8))) __bf16 bf16x8;
typedef __attribute__((ext_vector_type(4))) float f32x4;

static __device__ inline unsigned short f2bfu(float f) {
    unsigned u = __builtin_bit_cast(unsigned, f);
    u += 0x7fffu + ((u >> 16) & 1u);
    return (unsigned short)(u >> 16);
}
static __device__ inline unsigned packbf(float a, float b) {
    return (unsigned)f2bfu(a) | ((unsigned)f2bfu(b) << 16);
}
static __device__ inline float bfl(unsigned u) {
    unsigned x = u << 16; return __builtin_bit_cast(float, x);
}
static __device__ inline float bfh(unsigned u) {
    unsigned x = u & 0xffff0000u; return __builtin_bit_cast(float, x);
}
static __device__ inline bf16x8 pack8(float4 a, float4 b) {
    union { unsigned u[4]; bf16x8 v; } r;
    r.u[0] = packbf(a.x, a.y); r.u[1] = packbf(a.z, a.w);
    r.u[2] = packbf(b.x, b.y); r.u[3] = packbf(b.z, b.w);
    return r.v;
}

// ---------------- segment boundaries (batch is sorted) ----------------
__global__ void seg_bounds_kernel(const int* __restrict__ batch, int n,
                                  int* __restrict__ seg_start) {
    int b = threadIdx.x;
    if (b > B_SEGS) return;
    int lo = 0, hi = n;
    while (lo < hi) {
        int mid = (lo + hi) >> 1;
        if (batch[mid] < b) lo = mid + 1; else hi = mid;
    }
    seg_start[b] = lo;
}

// ------- one-time weight conversion fp32 -> bf16 (packed u32), global -------
__global__ __launch_bounds__(256) void wconv_kernel(
        const float* __restrict__ W_in, const float* __restrict__ W_a,
        const float* __restrict__ W_out, unsigned* __restrict__ Wb,
        unsigned* __restrict__ Wa, unsigned* __restrict__ Wo,
        unsigned* __restrict__ Wagg) {
    int i = blockIdx.x * 256 + threadIdx.x;
    if (i < 8192) {
        float2 v = *(const float2*)(W_in + (size_t)i * 2);
        Wb[i] = packbf(v.x, v.y);
    } else if (i < 9216) {
        int j = i - 8192;
        if (j < 512) {
            float2 v = *(const float2*)(W_a + (size_t)j * 2);
            Wa[j] = packbf(v.x, v.y);
        } else Wa[j] = 0u;
    } else if (i < 17408) {
        int j = i - 9216;
        int row = j >> 7, cu = j & 127;
        float2 v = *(const float2*)(W_out + (size_t)row * H_DIM + cu * 2);
        Wo[j] = packbf(v.x, v.y);
    } else if (i < 82944) {
        int j = i - 17408;
        int row = j >> 10, cu = j & 1023;
        float2 v = *(const float2*)(W_out + (size_t)row * H_DIM + 256 + cu * 2);
        Wagg[j] = packbf(v.x, v.y);
    }
}

// ---- segment-major mega: one block per segment, 1024 threads (16 waves) ----
// R14 body + (a) last-chunk out_part held in registers (skips 25MB global
// roundtrip for ~98% of rows), (b) uint4 agg loop (4x fewer agg LDS instrs)
// merged via shfl_xor. launch_bounds(1024): hard VGPR cap 128; R6/R7/R10/R12
// spills all came from tighter caps or 256-thr global-frag addressing.
__global__ __launch_bounds__(1024) void mega_kernel(
        const float* __restrict__ x, const int* __restrict__ seg_start,
        const float* __restrict__ b_in, const float* __restrict__ b_a,
        const float* __restrict__ b_out, const unsigned* __restrict__ Wb,
        const unsigned* __restrict__ Wa, const unsigned* __restrict__ Wo,
        const unsigned* __restrict__ Wagg, unsigned* __restrict__ out_part_u32,
        float* __restrict__ out) {
    __shared__ __align__(16) unsigned WbL[128 * 68];   // W_in bf16
    __shared__ __align__(16) unsigned WaL[16 * 68];    // W_a bf16 (8..15 zero)
    __shared__ __align__(16) unsigned WoL[64 * 132];   // W_out[:, :256] bf16
    __shared__ __align__(16) unsigned XP[256 * 68];    // xp chunk bf16 / agg f32
    __shared__ float scoref[256 * 8];
    __shared__ float projL[64];
    unsigned short* XPs = (unsigned short*)XP;
    float* XPf = (float*)XP;
    unsigned short* opart16 = (unsigned short*)out_part_u32;

    const int b = blockIdx.x;
    const int s0 = seg_start[b], s1 = seg_start[b + 1];
    const int cnt = s1 - s0;
    if (cnt == 0) return;
    const int t = threadIdx.x;
    const int last_c0 = s0 + ((cnt - 1) >> 8) * 256;   // start of final chunk

    // ---- stage weights: pure uint4 copies from pre-converted bf16 global ----
    {
        const uint4* srcb = (const uint4*)Wb;
#pragma unroll
        for (int i = 0; i < 2; ++i) {
            int idx = i * 1024 + t;
            int row = idx >> 4, c4 = idx & 15;
            *(uint4*)&WbL[row * 68 + c4 * 4] = srcb[idx];
        }
        const uint4* srco = (const uint4*)Wo;
#pragma unroll
        for (int i = 0; i < 2; ++i) {
            int idx = i * 1024 + t;
            int row = idx >> 5, c4 = idx & 31;
            *(uint4*)&WoL[row * 132 + c4 * 4] = srco[idx];
        }
        if (t < 256) {
            const uint4* sa = (const uint4*)Wa;
            int row = t >> 4, c4 = t & 15;
            *(uint4*)&WaL[row * 68 + c4 * 4] = sa[t];
        }
    }
    __syncthreads();

    const int w = t >> 6, l = t & 63, lr = l & 15, lk = l >> 4;
    // agg ownership: slot = (head a0, feature-quad q4); group g = row mod 8
    const int slot = t >> 3, g = t & 7;
    const int a0 = slot >> 4, q4 = slot & 15;

    float binv[8];
#pragma unroll
    for (int nr = 0; nr < 8; ++nr) binv[nr] = b_in[nr * 16 + lr];
    const float ba = b_a[lr & 7];

    const f32x4 z4 = {0.f, 0.f, 0.f, 0.f};
    float sm[8], mx[8];
#pragma unroll
    for (int j = 0; j < 8; ++j) { sm[j] = 0.f; mx[j] = -INFINITY; }
    f32x4 aco[4];   // out_part accumulators; final chunk's values stay live

    for (int c0 = s0; c0 < s1; c0 += 256) {
        const int rc = min(256, s1 - c0);
        const int arowc = min(c0 + w * 16 + lr, s1 - 1);

        bf16x8 af[4];
#pragma unroll
        for (int ks = 0; ks < 4; ++ks) {
            const float4* xp4 = (const float4*)(x + (size_t)arowc * 128 + ks * 32 + lk * 8);
            af[ks] = pack8(xp4[0], xp4[1]);
        }

        // xp GEMM in two nr-halves (acc[4] caps register pressure; proven)
#pragma unroll
        for (int nh = 0; nh < 2; ++nh) {
            f32x4 acc[4];
#pragma unroll
            for (int nr = 0; nr < 4; ++nr) acc[nr] = z4;
#pragma unroll
            for (int ks = 0; ks < 4; ++ks)
#pragma unroll
                for (int nr = 0; nr < 4; ++nr) {
                    bf16x8 bfrag = *(const bf16x8*)&WbL[((nh * 4 + nr) * 16 + lr) * 68 + ks * 16 + lk * 4];
                    acc[nr] = __builtin_amdgcn_mfma_f32_16x16x32_bf16(af[ks], bfrag, acc[nr], 0, 0, 0);
                }
#pragma unroll
            for (int nr = 0; nr < 4; ++nr)
#pragma unroll
                for (int r = 0; r < 4; ++r) {
                    int row = w * 16 + lk * 4 + r;
                    XPs[row * 136 + (nh * 4 + nr) * 16 + lr] =
                        f2bfu(((const float*)&acc[nr])[r] + binv[nh * 4 + nr]);
                }
        }
        // own XP rows back as A-frags (same-wave write/read)
        bf16x8 xf[4];
#pragma unroll
        for (int ks = 0; ks < 4; ++ks)
            xf[ks] = *(const bf16x8*)&XPs[(w * 16 + lr) * 136 + ks * 32 + lk * 8];
        // score MFMA
        f32x4 sacc = z4;
#pragma unroll
        for (int ks = 0; ks < 4; ++ks) {
            bf16x8 bfrag = *(const bf16x8*)&WaL[lr * 68 + ks * 16 + lk * 4];
            sacc = __builtin_amdgcn_mfma_f32_16x16x32_bf16(xf[ks], bfrag, sacc, 0, 0, 0);
        }
        if (lr < A_HEADS) {
#pragma unroll
            for (int r = 0; r < 4; ++r) {
                int row = w * 16 + lk * 4 + r;
                scoref[row * 8 + lr] = __expf(-fabsf(((const float*)&sacc)[r] + ba));
            }
        }
        // out_part GEMM K=256 (B-frags from LDS WoL)
#pragma unroll
        for (int nr = 0; nr < 4; ++nr) aco[nr] = z4;
#pragma unroll
        for (int ks = 0; ks < 4; ++ks)
#pragma unroll
            for (int nr = 0; nr < 4; ++nr) {
                bf16x8 b0 = *(const bf16x8*)&WoL[(nr * 16 + lr) * 132 + ks * 16 + lk * 4];
                aco[nr] = __builtin_amdgcn_mfma_f32_16x16x32_bf16(af[ks], b0, aco[nr], 0, 0, 0);
                bf16x8 b1 = *(const bf16x8*)&WoL[(nr * 16 + lr) * 132 + 64 + ks * 16 + lk * 4];
                aco[nr] = __builtin_amdgcn_mfma_f32_16x16x32_bf16(xf[ks], b1, aco[nr], 0, 0, 0);
            }
        if (c0 != last_c0) {   // non-final chunk: spill out_part to global
#pragma unroll
            for (int nr = 0; nr < 4; ++nr)
#pragma unroll
                for (int r = 0; r < 4; ++r) {
                    int n = c0 + w * 16 + lk * 4 + r;
                    opart16[(size_t)n * 64 + nr * 16 + lr] = f2bfu(((const float*)&aco[nr])[r]);
                }
        }
        __syncthreads();   // XP + scoref visible to all waves

        // uint4 agg: thread = (a0, q4=8 feats), rows i ≡ g (mod 8)
        for (int i = g; i < rc; i += 8) {
            uint4 v = *(const uint4*)&XP[i * 68 + q4 * 4];
            float sa = scoref[i * 8 + a0];
            float e;
            e = sa * bfl(v.x); sm[0] += e; mx[0] = fmaxf(mx[0], e);
            e = sa * bfh(v.x); sm[1] += e; mx[1] = fmaxf(mx[1], e);
            e = sa * bfl(v.y); sm[2] += e; mx[2] = fmaxf(mx[2], e);
            e = sa * bfh(v.y); sm[3] += e; mx[3] = fmaxf(mx[3], e);
            e = sa * bfl(v.z); sm[4] += e; mx[4] = fmaxf(mx[4], e);
            e = sa * bfh(v.z); sm[5] += e; mx[5] = fmaxf(mx[5], e);
            e = sa * bfl(v.w); sm[6] += e; mx[6] = fmaxf(mx[6], e);
            e = sa * bfh(v.w); sm[7] += e; mx[7] = fmaxf(mx[7], e);
        }
        __syncthreads();   // before next chunk overwrites XP/scoref
    }

    // ---- merge the 8 row-groups via shfl_xor (g lives in lane bits 0..2) ----
#pragma unroll
    for (int d = 1; d < 8; d <<= 1)
#pragma unroll
        for (int j = 0; j < 8; ++j) {
            sm[j] += __shfl_xor(sm[j], d);
            mx[j] = fmaxf(mx[j], __shfl_xor(mx[j], d));
        }
    if (g == 0) {
        const float inv = 1.f / (float)cnt;
        float4 s0v = make_float4(sm[0] * inv, sm[1] * inv, sm[2] * inv, sm[3] * inv);
        float4 s1v = make_float4(sm[4] * inv, sm[5] * inv, sm[6] * inv, sm[7] * inv);
        *(float4*)&XPf[a0 * 256 + q4 * 8]       = s0v;
        *(float4*)&XPf[a0 * 256 + q4 * 8 + 4]   = s1v;
        *(float4*)&XPf[a0 * 256 + 128 + q4 * 8]     = make_float4(mx[0], mx[1], mx[2], mx[3]);
        *(float4*)&XPf[a0 * 256 + 128 + q4 * 8 + 4] = make_float4(mx[4], mx[5], mx[6], mx[7]);
    }
    __syncthreads();

    // ---- projection via bf16 Wagg (global, L2-hot): wave w -> 4 outputs ----
#pragma unroll
    for (int i = 0; i < 4; ++i) {
        int o = w * 4 + i;
        const unsigned* wrow = Wagg + (size_t)o * 1024;
        float partial = 0.f;
#pragma unroll
        for (int c = 0; c < 4; ++c) {
            int j4 = c * 256 + l * 4;
            uint4 wv = *(const uint4*)&wrow[j4];
            const float* av = &XPf[2 * j4];
            partial = fmaf(bfl(wv.x), av[0], partial);
            partial = fmaf(bfh(wv.x), av[1], partial);
            partial = fmaf(bfl(wv.y), av[2], partial);
            partial = fmaf(bfh(wv.y), av[3], partial);
            partial = fmaf(bfl(wv.z), av[4], partial);
            partial = fmaf(bfh(wv.z), av[5], partial);
            partial = fmaf(bfl(wv.w), av[6], partial);
            partial = fmaf(bfh(wv.w), av[7], partial);
        }
#pragma unroll
        for (int m = 1; m < 64; m <<= 1) partial += __shfl_xor(partial, m);
        if (l == 0) projL[o] = partial + b_out[o];
    }
    __syncthreads();

    // ---- final A: earlier chunks (rare) from global out_part ----
    {
        const int rr = t >> 3, cg = t & 7;
        float p[8];
#pragma unroll
        for (int j = 0; j < 8; ++j) p[j] = projL[cg * 8 + j];
        for (int row = s0 + rr; row < last_c0; row += 128) {
            uint4 v = *(const uint4*)&out_part_u32[(size_t)row * 32 + cg * 4];
            float4 o0, o1;
            o0.x = fmaxf(bfl(v.x) + p[0], 0.f);
            o0.y = fmaxf(bfh(v.x) + p[1], 0.f);
            o0.z = fmaxf(bfl(v.y) + p[2], 0.f);
            o0.w = fmaxf(bfh(v.y) + p[3], 0.f);
            o1.x = fmaxf(bfl(v.z) + p[4], 0.f);
            o1.y = fmaxf(bfh(v.z) + p[5], 0.f);
            o1.z = fmaxf(bfl(v.w) + p[6], 0.f);
            o1.w = fmaxf(bfh(v.w) + p[7], 0.f);
            *(float4*)&out[(size_t)row * 64 + cg * 8] = o0;
            *(float4*)&out[(size_t)row * 64 + cg * 8 + 4] = o1;
        }
    }
    // ---- final B: last chunk straight from registers ----
    {
        float pj[4];
#pragma unroll
        for (int nr = 0; nr < 4; ++nr) pj[nr] = projL[nr * 16 + lr];
#pragma unroll
        for (int r = 0; r < 4; ++r) {
            int n = last_c0 + w * 16 + lk * 4 + r;
            if (n < s1) {
#pragma unroll
                for (int nr = 0; nr < 4; ++nr)
                    out[(size_t)n * 64 + nr * 16 + lr] =
                        fmaxf(((const float*)&aco[nr])[r] + pj[nr], 0.f);
            }
        }
    }
}

extern "C" void kernel_launch(void* const* d_in, const int* in_sizes, int n_in,
                              void* d_out, int out_size, void* d_ws, size_t ws_size,
                              hipStream_t stream) {
    const float* x     = (const float*)d_in[0];
    const int*   batch = (const int*)d_in[1];
    const float* W_in  = (const float*)d_in[3];
    const float* b_in  = (const float*)d_in[4];
    const float* W_a   = (const float*)d_in[5];
    const float* b_a   = (const float*)d_in[6];
    const float* W_out = (const float*)d_in[7];
    const float* b_out = (const float*)d_in[8];
    float* out = (float*)d_out;

    int* seg_start  = (int*)d_ws;                            // 520 ints
    unsigned* Wb    = (unsigned*)(seg_start + 520);          // 8192
    unsigned* Wa    = Wb + 8192;                             // 1024
    unsigned* Wo    = Wa + 1024;                             // 8192
    unsigned* Wagg  = Wo + 8192;                             // 65536
    unsigned* out_part_u32 = Wagg + 65536;                   // N*32 u32

    seg_bounds_kernel<<<1, 1024, 0, stream>>>(batch, N_NODES, seg_start);
    wconv_kernel<<<324, 256, 0, stream>>>(W_in, W_a, W_out, Wb, Wa, Wo, Wagg);
    mega_kernel<<<B_SEGS, 1024, 0, stream>>>(
        x, seg_start, b_in, b_a, b_out, Wb, Wa, Wo, Wagg, out_part_u32, out);
}

// Round 16
// 61.570 us; speedup vs baseline: 2.9082x; 1.0864x over previous
//
#include <hip/hip_runtime.h>
#include <math.h>

#define N_NODES 100000
#define D_INPUT 128
#define FDIM 128
#define A_HEADS 8
#define B_SEGS 512
#define D_OUTPUT 64
#define H_DIM 2304

typedef __attribute__((ext_vector_type(8))) __bf16 bf16x8;
typedef __attribute__((ext_vector_type(4))) float f32x4;

static __device__ inline unsigned short f2bfu(float f) {
    unsigned u = __builtin_bit_cast(unsigned, f);
    u += 0x7fffu + ((u >> 16) & 1u);
    return (unsigned short)(u >> 16);
}
static __device__ inline unsigned packbf(float a, float b) {
    return (unsigned)f2bfu(a) | ((unsigned)f2bfu(b) << 16);
}
static __device__ inline float bfl(unsigned u) {
    unsigned x = u << 16; return __builtin_bit_cast(float, x);
}
static __device__ inline float bfh(unsigned u) {
    unsigned x = u & 0xffff0000u; return __builtin_bit_cast(float, x);
}
static __device__ inline bf16x8 pack8(float4 a, float4 b) {
    union { unsigned u[4]; bf16x8 v; } r;
    r.u[0] = packbf(a.x, a.y); r.u[1] = packbf(a.z, a.w);
    r.u[2] = packbf(b.x, b.y); r.u[3] = packbf(b.z, b.w);
    return r.v;
}

// ---------------- segment boundaries (batch is sorted) ----------------
__global__ void seg_bounds_kernel(const int* __restrict__ batch, int n,
                                  int* __restrict__ seg_start) {
    int b = threadIdx.x;
    if (b > B_SEGS) return;
    int lo = 0, hi = n;
    while (lo < hi) {
        int mid = (lo + hi) >> 1;
        if (batch[mid] < b) lo = mid + 1; else hi = mid;
    }
    seg_start[b] = lo;
}

// ------- one-time weight conversion fp32 -> bf16 (packed u32), global -------
__global__ __launch_bounds__(256) void wconv_kernel(
        const float* __restrict__ W_in, const float* __restrict__ W_a,
        const float* __restrict__ W_out, unsigned* __restrict__ Wb,
        unsigned* __restrict__ Wa, unsigned* __restrict__ Wo,
        unsigned* __restrict__ Wagg) {
    int i = blockIdx.x * 256 + threadIdx.x;
    if (i < 8192) {
        float2 v = *(const float2*)(W_in + (size_t)i * 2);
        Wb[i] = packbf(v.x, v.y);
    } else if (i < 9216) {
        int j = i - 8192;
        if (j < 512) {
            float2 v = *(const float2*)(W_a + (size_t)j * 2);
            Wa[j] = packbf(v.x, v.y);
        } else Wa[j] = 0u;
    } else if (i < 17408) {
        int j = i - 9216;
        int row = j >> 7, cu = j & 127;
        float2 v = *(const float2*)(W_out + (size_t)row * H_DIM + cu * 2);
        Wo[j] = packbf(v.x, v.y);
    } else if (i < 82944) {
        int j = i - 17408;
        int row = j >> 10, cu = j & 1023;
        float2 v = *(const float2*)(W_out + (size_t)row * H_DIM + 256 + cu * 2);
        Wagg[j] = packbf(v.x, v.y);
    }
}

// ---- segment-major mega: one block per segment, 1024 threads (16 waves) ----
// R15 body + conflict-free agg mapping: per iteration a wave reads the SAME
// 4 XP rows (8 u32/bank structural min on b128; scoref becomes broadcast).
// Merge: 2x shfl_xor (row-subgroup in lane bits) + one 16-lane LDS pairwise
// merge across wave-halves. First chunk's x loads issued before the staging
// barrier. launch_bounds(1024): hard VGPR cap 128 (spill history: R6/7/10/12).
__global__ __launch_bounds__(1024) void mega_kernel(
        const float* __restrict__ x, const int* __restrict__ seg_start,
        const float* __restrict__ b_in, const float* __restrict__ b_a,
        const float* __restrict__ b_out, const unsigned* __restrict__ Wb,
        const unsigned* __restrict__ Wa, const unsigned* __restrict__ Wo,
        const unsigned* __restrict__ Wagg, unsigned* __restrict__ out_part_u32,
        float* __restrict__ out) {
    __shared__ __align__(16) unsigned WbL[128 * 68];   // W_in bf16
    __shared__ __align__(16) unsigned WaL[16 * 68];    // W_a bf16 (8..15 zero)
    __shared__ __align__(16) unsigned WoL[64 * 132];   // W_out[:, :256] bf16
    __shared__ __align__(16) unsigned XP[256 * 68];    // xp chunk bf16 / agg f32
    __shared__ float scoref[256 * 8];                  // scores / merge buffer
    __shared__ float projL[64];
    unsigned short* XPs = (unsigned short*)XP;
    float* XPf = (float*)XP;
    unsigned short* opart16 = (unsigned short*)out_part_u32;

    const int b = blockIdx.x;
    const int s0 = seg_start[b], s1 = seg_start[b + 1];
    const int cnt = s1 - s0;
    if (cnt == 0) return;
    const int t = threadIdx.x;
    const int last_c0 = s0 + ((cnt - 1) >> 8) * 256;   // start of final chunk

    const int w = t >> 6, l = t & 63, lr = l & 15, lk = l >> 4;
    // agg ownership (conflict-free): feature quad q4 = l&15, row subgroup
    // gq = l>>4 (in-lane for shfl), head a0h = w&7, half gh = w>>3.
    const int q4 = l & 15, gq = l >> 4, a0h = w & 7, gh = w >> 3;
    const int g = gh * 4 + gq;    // row group 0..7

    // ---- stage weights (issue) ----
    {
        const uint4* srcb = (const uint4*)Wb;
#pragma unroll
        for (int i = 0; i < 2; ++i) {
            int idx = i * 1024 + t;
            int row = idx >> 4, c4 = idx & 15;
            *(uint4*)&WbL[row * 68 + c4 * 4] = srcb[idx];
        }
        const uint4* srco = (const uint4*)Wo;
#pragma unroll
        for (int i = 0; i < 2; ++i) {
            int idx = i * 1024 + t;
            int row = idx >> 5, c4 = idx & 31;
            *(uint4*)&WoL[row * 132 + c4 * 4] = srco[idx];
        }
        if (t < 256) {
            const uint4* sa = (const uint4*)Wa;
            int row = t >> 4, c4 = t & 15;
            *(uint4*)&WaL[row * 68 + c4 * 4] = sa[t];
        }
    }
    // ---- peel first chunk's x load: in flight through staging + barrier ----
    bf16x8 af[4];
    {
        const int arowc = min(s0 + w * 16 + lr, s1 - 1);
#pragma unroll
        for (int ks = 0; ks < 4; ++ks) {
            const float4* xp4 = (const float4*)(x + (size_t)arowc * 128 + ks * 32 + lk * 8);
            af[ks] = pack8(xp4[0], xp4[1]);
        }
    }
    __syncthreads();

    float binv[8];
#pragma unroll
    for (int nr = 0; nr < 8; ++nr) binv[nr] = b_in[nr * 16 + lr];
    const float ba = b_a[lr & 7];

    const f32x4 z4 = {0.f, 0.f, 0.f, 0.f};
    float sm[8], mx[8];
#pragma unroll
    for (int j = 0; j < 8; ++j) { sm[j] = 0.f; mx[j] = -INFINITY; }
    f32x4 aco[4];   // out_part accumulators; final chunk's values stay live

    for (int c0 = s0; c0 < s1; c0 += 256) {
        const int rc = min(256, s1 - c0);
        if (c0 != s0) {   // later chunks (rare): load fresh
            const int arowc = min(c0 + w * 16 + lr, s1 - 1);
#pragma unroll
            for (int ks = 0; ks < 4; ++ks) {
                const float4* xp4 = (const float4*)(x + (size_t)arowc * 128 + ks * 32 + lk * 8);
                af[ks] = pack8(xp4[0], xp4[1]);
            }
        }

        // xp GEMM in two nr-halves (acc[4] caps register pressure; proven)
#pragma unroll
        for (int nh = 0; nh < 2; ++nh) {
            f32x4 acc[4];
#pragma unroll
            for (int nr = 0; nr < 4; ++nr) acc[nr] = z4;
#pragma unroll
            for (int ks = 0; ks < 4; ++ks)
#pragma unroll
                for (int nr = 0; nr < 4; ++nr) {
                    bf16x8 bfrag = *(const bf16x8*)&WbL[((nh * 4 + nr) * 16 + lr) * 68 + ks * 16 + lk * 4];
                    acc[nr] = __builtin_amdgcn_mfma_f32_16x16x32_bf16(af[ks], bfrag, acc[nr], 0, 0, 0);
                }
#pragma unroll
            for (int nr = 0; nr < 4; ++nr)
#pragma unroll
                for (int r = 0; r < 4; ++r) {
                    int row = w * 16 + lk * 4 + r;
                    XPs[row * 136 + (nh * 4 + nr) * 16 + lr] =
                        f2bfu(((const float*)&acc[nr])[r] + binv[nh * 4 + nr]);
                }
        }
        // own XP rows back as A-frags (same-wave write/read)
        bf16x8 xf[4];
#pragma unroll
        for (int ks = 0; ks < 4; ++ks)
            xf[ks] = *(const bf16x8*)&XPs[(w * 16 + lr) * 136 + ks * 32 + lk * 8];
        // score MFMA
        f32x4 sacc = z4;
#pragma unroll
        for (int ks = 0; ks < 4; ++ks) {
            bf16x8 bfrag = *(const bf16x8*)&WaL[lr * 68 + ks * 16 + lk * 4];
            sacc = __builtin_amdgcn_mfma_f32_16x16x32_bf16(xf[ks], bfrag, sacc, 0, 0, 0);
        }
        if (lr < A_HEADS) {
#pragma unroll
            for (int r = 0; r < 4; ++r) {
                int row = w * 16 + lk * 4 + r;
                scoref[row * 8 + lr] = __expf(-fabsf(((const float*)&sacc)[r] + ba));
            }
        }
        // out_part GEMM K=256 (B-frags from LDS WoL)
#pragma unroll
        for (int nr = 0; nr < 4; ++nr) aco[nr] = z4;
#pragma unroll
        for (int ks = 0; ks < 4; ++ks)
#pragma unroll
            for (int nr = 0; nr < 4; ++nr) {
                bf16x8 b0 = *(const bf16x8*)&WoL[(nr * 16 + lr) * 132 + ks * 16 + lk * 4];
                aco[nr] = __builtin_amdgcn_mfma_f32_16x16x32_bf16(af[ks], b0, aco[nr], 0, 0, 0);
                bf16x8 b1 = *(const bf16x8*)&WoL[(nr * 16 + lr) * 132 + 64 + ks * 16 + lk * 4];
                aco[nr] = __builtin_amdgcn_mfma_f32_16x16x32_bf16(xf[ks], b1, aco[nr], 0, 0, 0);
            }
        if (c0 != last_c0) {   // non-final chunk: spill out_part to global
#pragma unroll
            for (int nr = 0; nr < 4; ++nr)
#pragma unroll
                for (int r = 0; r < 4; ++r) {
                    int n = c0 + w * 16 + lk * 4 + r;
                    opart16[(size_t)n * 64 + nr * 16 + lr] = f2bfu(((const float*)&aco[nr])[r]);
                }
        }
        __syncthreads();   // XP + scoref visible to all waves

        // agg: wave reads rows i = g+8j (4 rows per wave-iter, bank-balanced);
        // scoref read is a 4-address broadcast.
        for (int i = g; i < rc; i += 8) {
            uint4 v = *(const uint4*)&XP[i * 68 + q4 * 4];
            float sa = scoref[i * 8 + a0h];
            float e;
            e = sa * bfl(v.x); sm[0] += e; mx[0] = fmaxf(mx[0], e);
            e = sa * bfh(v.x); sm[1] += e; mx[1] = fmaxf(mx[1], e);
            e = sa * bfl(v.y); sm[2] += e; mx[2] = fmaxf(mx[2], e);
            e = sa * bfh(v.y); sm[3] += e; mx[3] = fmaxf(mx[3], e);
            e = sa * bfl(v.z); sm[4] += e; mx[4] = fmaxf(mx[4], e);
            e = sa * bfh(v.z); sm[5] += e; mx[5] = fmaxf(mx[5], e);
            e = sa * bfl(v.w); sm[6] += e; mx[6] = fmaxf(mx[6], e);
            e = sa * bfh(v.w); sm[7] += e; mx[7] = fmaxf(mx[7], e);
        }
        if (c0 + 256 < s1) __syncthreads();   // only if another chunk follows
    }

    // ---- merge gq subgroups in-wave (gq = lane bits 4..5) ----
#pragma unroll
    for (int d = 16; d <= 32; d <<= 1)
#pragma unroll
        for (int j = 0; j < 8; ++j) {
            sm[j] += __shfl_xor(sm[j], d);
            mx[j] = fmaxf(mx[j], __shfl_xor(mx[j], d));
        }
    __syncthreads();   // all agg reads done; scoref reusable as merge buffer
    if (gh == 1 && l < 16) {
        float* dst = &scoref[(a0h * 16 + l) * 16];
        *(float4*)&dst[0]  = make_float4(sm[0], sm[1], sm[2], sm[3]);
        *(float4*)&dst[4]  = make_float4(sm[4], sm[5], sm[6], sm[7]);
        *(float4*)&dst[8]  = make_float4(mx[0], mx[1], mx[2], mx[3]);
        *(float4*)&dst[12] = make_float4(mx[4], mx[5], mx[6], mx[7]);
    }
    __syncthreads();
    if (gh == 0 && l < 16) {
        const float* src = &scoref[(a0h * 16 + l) * 16];
        float4 s0v = *(const float4*)&src[0], s1v = *(const float4*)&src[4];
        float4 m0v = *(const float4*)&src[8], m1v = *(const float4*)&src[12];
        const float inv = 1.f / (float)cnt;
        float4 a0o = make_float4((sm[0] + s0v.x) * inv, (sm[1] + s0v.y) * inv,
                                 (sm[2] + s0v.z) * inv, (sm[3] + s0v.w) * inv);
        float4 a1o = make_float4((sm[4] + s1v.x) * inv, (sm[5] + s1v.y) * inv,
                                 (sm[6] + s1v.z) * inv, (sm[7] + s1v.w) * inv);
        *(float4*)&XPf[a0h * 256 + l * 8]     = a0o;
        *(float4*)&XPf[a0h * 256 + l * 8 + 4] = a1o;
        *(float4*)&XPf[a0h * 256 + 128 + l * 8] =
            make_float4(fmaxf(mx[0], m0v.x), fmaxf(mx[1], m0v.y),
                        fmaxf(mx[2], m0v.z), fmaxf(mx[3], m0v.w));
        *(float4*)&XPf[a0h * 256 + 128 + l * 8 + 4] =
            make_float4(fmaxf(mx[4], m1v.x), fmaxf(mx[5], m1v.y),
                        fmaxf(mx[6], m1v.z), fmaxf(mx[7], m1v.w));
    }
    __syncthreads();

    // ---- projection via bf16 Wagg (global, L2-hot): wave w -> 4 outputs ----
#pragma unroll
    for (int i = 0; i < 4; ++i) {
        int o = w * 4 + i;
        const unsigned* wrow = Wagg + (size_t)o * 1024;
        float partial = 0.f;
#pragma unroll
        for (int c = 0; c < 4; ++c) {
            int j4 = c * 256 + l * 4;
            uint4 wv = *(const uint4*)&wrow[j4];
            const float* av = &XPf[2 * j4];
            partial = fmaf(bfl(wv.x), av[0], partial);
            partial = fmaf(bfh(wv.x), av[1], partial);
            partial = fmaf(bfl(wv.y), av[2], partial);
            partial = fmaf(bfh(wv.y), av[3], partial);
            partial = fmaf(bfl(wv.z), av[4], partial);
            partial = fmaf(bfh(wv.z), av[5], partial);
            partial = fmaf(bfl(wv.w), av[6], partial);
            partial = fmaf(bfh(wv.w), av[7], partial);
        }
#pragma unroll
        for (int m = 1; m < 64; m <<= 1) partial += __shfl_xor(partial, m);
        if (l == 0) projL[o] = partial + b_out[o];
    }
    __syncthreads();

    // ---- final A: earlier chunks (rare) from global out_part ----
    {
        const int rr = t >> 3, cg = t & 7;
        float p[8];
#pragma unroll
        for (int j = 0; j < 8; ++j) p[j] = projL[cg * 8 + j];
        for (int row = s0 + rr; row < last_c0; row += 128) {
            uint4 v = *(const uint4*)&out_part_u32[(size_t)row * 32 + cg * 4];
            float4 o0, o1;
            o0.x = fmaxf(bfl(v.x) + p[0], 0.f);
            o0.y = fmaxf(bfh(v.x) + p[1], 0.f);
            o0.z = fmaxf(bfl(v.y) + p[2], 0.f);
            o0.w = fmaxf(bfh(v.y) + p[3], 0.f);
            o1.x = fmaxf(bfl(v.z) + p[4], 0.f);
            o1.y = fmaxf(bfh(v.z) + p[5], 0.f);
            o1.z = fmaxf(bfl(v.w) + p[6], 0.f);
            o1.w = fmaxf(bfh(v.w) + p[7], 0.f);
            *(float4*)&out[(size_t)row * 64 + cg * 8] = o0;
            *(float4*)&out[(size_t)row * 64 + cg * 8 + 4] = o1;
        }
    }
    // ---- final B: last chunk straight from registers ----
    {
        float pj[4];
#pragma unroll
        for (int nr = 0; nr < 4; ++nr) pj[nr] = projL[nr * 16 + lr];
#pragma unroll
        for (int r = 0; r < 4; ++r) {
            int n = last_c0 + w * 16 + lk * 4 + r;
            if (n < s1) {
#pragma unroll
                for (int nr = 0; nr < 4; ++nr)
                    out[(size_t)n * 64 + nr * 16 + lr] =
                        fmaxf(((const float*)&aco[nr])[r] + pj[nr], 0.f);
            }
        }
    }
}

extern "C" void kernel_launch(void* const* d_in, const int* in_sizes, int n_in,
                              void* d_out, int out_size, void* d_ws, size_t ws_size,
                              hipStream_t stream) {
    const float* x     = (const float*)d_in[0];
    const int*   batch = (const int*)d_in[1];
    const float* W_in  = (const float*)d_in[3];
    const float* b_in  = (const float*)d_in[4];
    const float* W_a   = (const float*)d_in[5];
    const float* b_a   = (const float*)d_in[6];
    const float* W_out = (const float*)d_in[7];
    const float* b_out = (const float*)d_in[8];
    float* out = (float*)d_out;

    int* seg_start  = (int*)d_ws;                            // 520 ints
    unsigned* Wb    = (unsigned*)(seg_start + 520);          // 8192
    unsigned* Wa    = Wb + 8192;                             // 1024
    unsigned* Wo    = Wa + 1024;                             // 8192
    unsigned* Wagg  = Wo + 8192;                             // 65536
    unsigned* out_part_u32 = Wagg + 65536;                   // N*32 u32

    seg_bounds_kernel<<<1, 1024, 0, stream>>>(batch, N_NODES, seg_start);
    wconv_kernel<<<324, 256, 0, stream>>>(W_in, W_a, W_out, Wb, Wa, Wo, Wagg);
    mega_kernel<<<B_SEGS, 1024, 0, stream>>>(
        x, seg_start, b_in, b_a, b_out, Wb, Wa, Wo, Wagg, out_part_u32, out);
}